// Round 11
// baseline (29.618 us; speedup 1.0000x reference)
//
#include <hip/hip_runtime.h>

#define NUM_C 128
#define SEESAW_EPS 1e-6f

typedef float f32x4 __attribute__((ext_vector_type(4)));

__global__ __launch_bounds__(1024) void seesaw_part_kernel(
    const float* __restrict__ logits,
    const int* __restrict__ targets,
    const float* __restrict__ s,
    float* __restrict__ partial,
    int n_rows)
{
    const int tid  = blockIdx.x * 1024 + threadIdx.x;
    const int lane = threadIdx.x & 63;
    const int half = lane >> 5;       // which of 2 consecutive rows in a load
    const int sub  = lane & 31;       // lane within the 32-lane row group
    const int wave = tid >> 6;
    const int base = wave << 3;       // 8 rows per wave, 4 independent chains

    // ---- issue ALL independent loads up front (2 KB logits / wave) ----
    // plain loads: nt halved L3 retention (R5/R9: FETCH ~66MB of 134MB)
    f32x4 v[4];
    int   t[4];
    bool  ok[4];
    #pragma unroll
    for (int c = 0; c < 4; ++c) {
        const int row = base + 2 * c + half;
        ok[c] = row < n_rows;
        const int r = ok[c] ? row : 0;
        v[c] = *reinterpret_cast<const f32x4*>(logits + (size_t)r * NUM_C + sub * 4);
        t[c] = targets[r];
    }
    __builtin_amdgcn_sched_barrier(0);

    f32x4 sv[4];
    #pragma unroll
    for (int c = 0; c < 4; ++c) {
        sv[c] = *reinterpret_cast<const f32x4*>(s + (size_t)t[c] * NUM_C + sub * 4);
    }

    // ---- unshifted exp (logits ~ N(0,1), no overflow; sigma shift-inv),
    //      den = dot(s[t,:], e)  (diag(s)==1), num = e[t] ----
    float den[4], num[4];
    #pragma unroll
    for (int c = 0; c < 4; ++c) {
        const float e0 = __expf(v[c].x), e1 = __expf(v[c].y);
        const float e2 = __expf(v[c].z), e3 = __expf(v[c].w);
        den[c] = e0 * sv[c].x + e1 * sv[c].y + e2 * sv[c].z + e3 * sv[c].w;
        const int r = t[c] & 3;
        const float pick = (r == 0) ? e0 : (r == 1) ? e1 : (r == 2) ? e2 : e3;
        num[c] = __shfl(pick, (half << 5) | (t[c] >> 2), 64);
    }

    // ---- den reduce over each 32-lane half; 4 chains interleaved ----
    #pragma unroll
    for (int off = 1; off <= 16; off <<= 1) {
        #pragma unroll
        for (int c = 0; c < 4; ++c)
            den[c] += __shfl_xor(den[c], off, 64);
    }

    float acc = 0.0f;
    if (sub == 0) {
        #pragma unroll
        for (int c = 0; c < 4; ++c) {
            if (ok[c]) {
                const float sig = num[c] / (den[c] + SEESAW_EPS);
                acc += -__logf(sig + SEESAW_EPS);
            }
        }
    }

    // ---- single-barrier hierarchical block reduce ----
    // acc is nonzero only on lanes 0 and 32; fold, one LDS word per wave.
    acc += __shfl_xor(acc, 32, 64);               // lane0 += lane32
    __shared__ float red[16];                     // 16 waves per block
    const int wid = threadIdx.x >> 6;
    if (lane == 0) red[wid] = acc;
    __syncthreads();
    if (threadIdx.x < 16) {
        float a = red[threadIdx.x];
        #pragma unroll
        for (int off = 1; off <= 8; off <<= 1) a += __shfl_xor(a, off, 64);
        if (threadIdx.x == 0) partial[blockIdx.x] = a;
    }
}

// Parallel tail: 256 threads, vectorized coalesced loads, all independent.
__global__ __launch_bounds__(256) void seesaw_reduce_kernel(
    const float* __restrict__ partial, float* __restrict__ out,
    int n, float inv_n)
{
    float a = 0.0f;
    const f32x4* p4 = reinterpret_cast<const f32x4*>(partial);
    const int n4 = n >> 2;
    #pragma unroll 8
    for (int i = threadIdx.x; i < n4; i += 256) {
        const f32x4 v = p4[i];
        a += (v.x + v.y) + (v.z + v.w);
    }
    for (int i = (n4 << 2) + threadIdx.x; i < n; i += 256) a += partial[i];

    #pragma unroll
    for (int off = 1; off <= 32; off <<= 1) a += __shfl_xor(a, off, 64);

    __shared__ float red[4];
    if ((threadIdx.x & 63) == 0) red[threadIdx.x >> 6] = a;
    __syncthreads();
    if (threadIdx.x == 0)
        out[0] = ((red[0] + red[1]) + (red[2] + red[3])) * inv_n;
}

extern "C" void kernel_launch(void* const* d_in, const int* in_sizes, int n_in,
                              void* d_out, int out_size, void* d_ws, size_t ws_size,
                              hipStream_t stream) {
    const float* logits  = (const float*)d_in[0];
    const int*   targets = (const int*)d_in[1];
    const float* s       = (const float*)d_in[2];
    float*       out     = (float*)d_out;
    float*       partial = (float*)d_ws;

    const int n_rows = in_sizes[1];                 // N = 262144
    const float inv_n = 1.0f / (float)n_rows;

    // 8 rows/wave, 16 waves/block -> 128 rows/block
    const int blocks = (n_rows + 127) / 128;        // 2048 for N=262144

    seesaw_part_kernel<<<blocks, 1024, 0, stream>>>(logits, targets, s,
                                                    partial, n_rows);
    seesaw_reduce_kernel<<<1, 256, 0, stream>>>(partial, out, blocks, inv_n);
}

// Round 12
// 27.904 us; speedup vs baseline: 1.0614x; 1.0614x over previous
//
#include <hip/hip_runtime.h>

#define NUM_C 128
#define SEESAW_EPS 1e-6f

typedef float f32x4 __attribute__((ext_vector_type(4)));

// Best-measured structure (R10, 27.95us): 256-thread blocks, 8 rows/wave in
// one burst, 4 independent chains, partials + parallel reduce tail.
// Model: bound by per-XCD L2 fill path (~5.2 TB/s chip-wide) for the 134MB
// zero-reuse logits stream; ~50% L3-hit (FETCH~66MB) doesn't lift it because
// L3-served bytes transit the same L2 fill path.
__global__ __launch_bounds__(256) void seesaw_part_kernel(
    const float* __restrict__ logits,
    const int* __restrict__ targets,
    const float* __restrict__ s,
    float* __restrict__ partial,
    int n_rows)
{
    const int tid  = blockIdx.x * 256 + threadIdx.x;
    const int lane = threadIdx.x & 63;
    const int half = lane >> 5;       // which of 2 consecutive rows in a load
    const int sub  = lane & 31;       // lane within the 32-lane row group
    const int wave = tid >> 6;
    const int base = wave << 3;       // 8 rows per wave, 4 independent chains

    // ---- issue ALL independent loads up front (2 KB logits / wave) ----
    f32x4 v[4];
    int   t[4];
    bool  ok[4];
    #pragma unroll
    for (int c = 0; c < 4; ++c) {
        const int row = base + 2 * c + half;
        ok[c] = row < n_rows;
        const int r = ok[c] ? row : 0;
        v[c] = *reinterpret_cast<const f32x4*>(logits + (size_t)r * NUM_C + sub * 4);
        t[c] = targets[r];
    }
    __builtin_amdgcn_sched_barrier(0);

    f32x4 sv[4];
    #pragma unroll
    for (int c = 0; c < 4; ++c) {
        sv[c] = *reinterpret_cast<const f32x4*>(s + (size_t)t[c] * NUM_C + sub * 4);
    }

    // ---- unshifted exp (logits ~ N(0,1), no overflow; sigma shift-inv),
    //      den = dot(s[t,:], e)  (diag(s)==1), num = e[t] ----
    float den[4], num[4];
    #pragma unroll
    for (int c = 0; c < 4; ++c) {
        const float e0 = __expf(v[c].x), e1 = __expf(v[c].y);
        const float e2 = __expf(v[c].z), e3 = __expf(v[c].w);
        den[c] = e0 * sv[c].x + e1 * sv[c].y + e2 * sv[c].z + e3 * sv[c].w;
        const int r = t[c] & 3;
        const float pick = (r == 0) ? e0 : (r == 1) ? e1 : (r == 2) ? e2 : e3;
        num[c] = __shfl(pick, (half << 5) | (t[c] >> 2), 64);
    }

    // ---- den reduce over each 32-lane half; 4 chains interleaved ----
    #pragma unroll
    for (int off = 1; off <= 16; off <<= 1) {
        #pragma unroll
        for (int c = 0; c < 4; ++c)
            den[c] += __shfl_xor(den[c], off, 64);
    }

    float acc = 0.0f;
    if (sub == 0) {
        #pragma unroll
        for (int c = 0; c < 4; ++c) {
            if (ok[c]) {
                const float sig = num[c] / (den[c] + SEESAW_EPS);
                acc += -__logf(sig + SEESAW_EPS);
            }
        }
    }

    // ---- block reduction -> one partial per block (no same-address atomics:
    //      ~10ns each serialized, R5; device-scope fences catastrophic, R9) ----
    __shared__ float red[256];
    red[threadIdx.x] = acc;
    __syncthreads();
    #pragma unroll
    for (int stride = 128; stride > 0; stride >>= 1) {
        if (threadIdx.x < stride) red[threadIdx.x] += red[threadIdx.x + stride];
        __syncthreads();
    }
    if (threadIdx.x == 0) partial[blockIdx.x] = red[0];
}

// Parallel tail: 1024 threads, vectorized coalesced loads, 2 iters/thread.
__global__ __launch_bounds__(1024) void seesaw_reduce_kernel(
    const float* __restrict__ partial, float* __restrict__ out,
    int n, float inv_n)
{
    float a = 0.0f;
    const f32x4* p4 = reinterpret_cast<const f32x4*>(partial);
    const int n4 = n >> 2;
    #pragma unroll 2
    for (int i = threadIdx.x; i < n4; i += 1024) {
        const f32x4 v = p4[i];
        a += (v.x + v.y) + (v.z + v.w);
    }
    for (int i = (n4 << 2) + threadIdx.x; i < n; i += 1024) a += partial[i];

    #pragma unroll
    for (int off = 1; off <= 32; off <<= 1) a += __shfl_xor(a, off, 64);

    __shared__ float red[16];
    if ((threadIdx.x & 63) == 0) red[threadIdx.x >> 6] = a;
    __syncthreads();
    if (threadIdx.x < 16) {
        float b = red[threadIdx.x];
        #pragma unroll
        for (int off = 1; off <= 8; off <<= 1) b += __shfl_xor(b, off, 64);
        if (threadIdx.x == 0) out[0] = b * inv_n;
    }
}

extern "C" void kernel_launch(void* const* d_in, const int* in_sizes, int n_in,
                              void* d_out, int out_size, void* d_ws, size_t ws_size,
                              hipStream_t stream) {
    const float* logits  = (const float*)d_in[0];
    const int*   targets = (const int*)d_in[1];
    const float* s       = (const float*)d_in[2];
    float*       out     = (float*)d_out;
    float*       partial = (float*)d_ws;

    const int n_rows = in_sizes[1];                 // N = 262144
    const float inv_n = 1.0f / (float)n_rows;

    // 8 rows per wave, 4 waves per block -> 32 rows per block
    const int blocks = (n_rows + 31) / 32;          // 8192 for N=262144

    seesaw_part_kernel<<<blocks, 256, 0, stream>>>(logits, targets, s,
                                                   partial, n_rows);
    seesaw_reduce_kernel<<<1, 1024, 0, stream>>>(partial, out, blocks, inv_n);
}